// Round 1
// baseline (3991.927 us; speedup 1.0000x reference)
//
#include <hip/hip_runtime.h>
#include <math.h>

#define NNODES 100000
#define HID 128
#define NLAYERS 4
#define NGRAPHS 200
#define NCLASSES 10
#define BN_EPS 1e-5f

// ---------------- small utility kernels ----------------

__global__ void k_transpose(const float* __restrict__ src, float* __restrict__ dst,
                            int J, int K) {
    // src [J][K] -> dst [K][J]
    int idx = blockIdx.x * blockDim.x + threadIdx.x;
    if (idx < J * K) {
        int j = idx / K, k = idx - j * K;
        dst[k * J + j] = src[idx];
    }
}

__global__ void k_deg(const int* __restrict__ ei, int E, int* __restrict__ deg) {
    int e = blockIdx.x * blockDim.x + threadIdx.x;
    if (e < E) atomicAdd(&deg[ei[E + e]], 1);
}

__global__ void k_scan1(const int* __restrict__ deg, int N,
                        int* __restrict__ rowstart, int* __restrict__ bsum) {
    __shared__ int s[256];
    int t = threadIdx.x;
    int i = blockIdx.x * 256 + t;
    int v = (i < N) ? deg[i] : 0;
    s[t] = v;
    __syncthreads();
    for (int off = 1; off < 256; off <<= 1) {
        int a = (t >= off) ? s[t - off] : 0;
        __syncthreads();
        s[t] += a;
        __syncthreads();
    }
    if (i < N) rowstart[i] = s[t] - v;      // exclusive within block
    if (t == 255) bsum[blockIdx.x] = s[255]; // block total
}

__global__ void k_scan2(const int* __restrict__ bsum, int nb, int* __restrict__ boff) {
    __shared__ int s[512];
    int t = threadIdx.x;
    int v = (t < nb) ? bsum[t] : 0;
    s[t] = v;
    __syncthreads();
    for (int off = 1; off < 512; off <<= 1) {
        int a = (t >= off) ? s[t - off] : 0;
        __syncthreads();
        s[t] += a;
        __syncthreads();
    }
    if (t < nb) boff[t] = s[t] - v; // exclusive
}

__global__ void k_scan3(int* __restrict__ rowstart, const int* __restrict__ boff,
                        int N, int E) {
    int i = blockIdx.x * 256 + threadIdx.x;
    if (i < N) rowstart[i] += boff[blockIdx.x];
    if (i == 0) rowstart[N] = E;
}

__global__ void k_fill(const int* __restrict__ ei, int E,
                       const int* __restrict__ rowstart, int* __restrict__ cursor,
                       int* __restrict__ col) {
    int e = blockIdx.x * blockDim.x + threadIdx.x;
    if (e < E) {
        int d = ei[E + e];
        int pos = atomicAdd(&cursor[d], 1);
        col[rowstart[d] + pos] = ei[e];
    }
}

// ---------------- matmul: out[N,128] = in[N,128] @ W[128,128] (W k-major) ----------------

__global__ __launch_bounds__(128) void k_matmul128(const float* __restrict__ in,
                                                   const float* __restrict__ W,
                                                   float* __restrict__ out, int N) {
    const int NB = 16;
    __shared__ float hs[NB][HID];
    int j = threadIdx.x; // 0..127
    int base = blockIdx.x * NB;
    if (base >= N) return;
    int nb = min(NB, N - base);
    for (int r = 0; r < nb; ++r) hs[r][j] = in[(base + r) * HID + j];
    __syncthreads();
    float acc[NB];
#pragma unroll
    for (int r = 0; r < NB; ++r) acc[r] = 0.f;
    for (int k4 = 0; k4 < HID / 4; ++k4) {
        int k = k4 * 4;
        float w0 = W[(k + 0) * HID + j];
        float w1 = W[(k + 1) * HID + j];
        float w2 = W[(k + 2) * HID + j];
        float w3 = W[(k + 3) * HID + j];
#pragma unroll
        for (int r = 0; r < NB; ++r) {
            float4 av = ((const float4*)hs[r])[k4];
            acc[r] = fmaf(av.x, w0, acc[r]);
            acc[r] = fmaf(av.y, w1, acc[r]);
            acc[r] = fmaf(av.z, w2, acc[r]);
            acc[r] = fmaf(av.w, w3, acc[r]);
        }
    }
    for (int r = 0; r < nb; ++r) out[(base + r) * HID + j] = acc[r];
}

// ---------------- CSR gather: agg[n] = sum over in-edges of m[src] ----------------

__global__ __launch_bounds__(256) void k_gather(const float* __restrict__ m,
                                                const int* __restrict__ rowstart,
                                                const int* __restrict__ col,
                                                float* __restrict__ agg, int N) {
    int node = blockIdx.x * 2 + (threadIdx.x >> 7);
    int f = threadIdx.x & 127;
    if (node >= N) return;
    int s = rowstart[node], e = rowstart[node + 1];
    float acc0 = 0.f, acc1 = 0.f;
    int i = s;
    for (; i + 1 < e; i += 2) {
        int c0 = col[i], c1 = col[i + 1];
        acc0 += m[c0 * HID + f];
        acc1 += m[c1 * HID + f];
    }
    if (i < e) acc0 += m[col[i] * HID + f];
    agg[node * HID + f] = acc0 + acc1;
}

// ---------------- fused GRU: gi = agg@w_ih^T+b_ih, gh = h@w_hh^T+b_hh, gate, h inplace --

__device__ __forceinline__ float sigmoidf_(float x) { return 1.0f / (1.0f + expf(-x)); }

__global__ __launch_bounds__(384) void k_gru(const float* __restrict__ agg,
                                             float* __restrict__ h,
                                             const float* __restrict__ wiT, // [128][384]
                                             const float* __restrict__ whT, // [128][384]
                                             const float* __restrict__ b_ih,
                                             const float* __restrict__ b_hh, int N) {
    const int NB = 16;
    __shared__ float as[NB][HID];
    __shared__ float hs[NB][HID];
    __shared__ float u[NB][256];   // r,z pre-activations
    __shared__ float gin[NB][HID]; // i_n
    __shared__ float ghn[NB][HID]; // h_n
    int j = threadIdx.x; // 0..383
    int base = blockIdx.x * NB;
    if (base >= N) return;
    int nb = min(NB, N - base);
    for (int idx = j; idx < nb * HID; idx += 384) {
        int r = idx >> 7, c = idx & 127;
        as[r][c] = agg[(base + r) * HID + c];
        hs[r][c] = h[(base + r) * HID + c];
    }
    __syncthreads();
    float ai[NB], ah[NB];
#pragma unroll
    for (int r = 0; r < NB; ++r) { ai[r] = 0.f; ah[r] = 0.f; }
    for (int k4 = 0; k4 < HID / 4; ++k4) {
        int k = k4 * 4;
        float wi0 = wiT[(k + 0) * 384 + j];
        float wi1 = wiT[(k + 1) * 384 + j];
        float wi2 = wiT[(k + 2) * 384 + j];
        float wi3 = wiT[(k + 3) * 384 + j];
        float wh0 = whT[(k + 0) * 384 + j];
        float wh1 = whT[(k + 1) * 384 + j];
        float wh2 = whT[(k + 2) * 384 + j];
        float wh3 = whT[(k + 3) * 384 + j];
#pragma unroll
        for (int r = 0; r < NB; ++r) {
            float4 av = ((const float4*)as[r])[k4];
            float4 hv = ((const float4*)hs[r])[k4];
            ai[r] = fmaf(av.x, wi0, ai[r]);
            ai[r] = fmaf(av.y, wi1, ai[r]);
            ai[r] = fmaf(av.z, wi2, ai[r]);
            ai[r] = fmaf(av.w, wi3, ai[r]);
            ah[r] = fmaf(hv.x, wh0, ah[r]);
            ah[r] = fmaf(hv.y, wh1, ah[r]);
            ah[r] = fmaf(hv.z, wh2, ah[r]);
            ah[r] = fmaf(hv.w, wh3, ah[r]);
        }
    }
    float bi = b_ih[j], bh = b_hh[j];
    for (int r = 0; r < nb; ++r) {
        float gi = ai[r] + bi;
        float gh = ah[r] + bh;
        if (j < 256) {
            u[r][j] = gi + gh;
        } else {
            gin[r][j - 256] = gi;
            ghn[r][j - 256] = gh;
        }
    }
    __syncthreads();
    if (j < HID) {
        for (int r = 0; r < nb; ++r) {
            float rr = sigmoidf_(u[r][j]);
            float zz = sigmoidf_(u[r][HID + j]);
            float nn = tanhf(gin[r][j] + rr * ghn[r][j]);
            float hv = hs[r][j];
            h[(base + r) * HID + j] = (1.f - zz) * nn + zz * hv;
        }
    }
}

// ---------------- BN stats / finalize / pool / head ----------------

__global__ __launch_bounds__(256) void k_bnstats(const float* __restrict__ y,
                                                 float* __restrict__ stats, int N) {
    int half = threadIdx.x >> 7, f = threadIdx.x & 127;
    float s = 0.f, s2 = 0.f;
    for (int n = blockIdx.x * 2 + half; n < N; n += gridDim.x * 2) {
        float v = y[n * HID + f];
        s += v;
        s2 += v * v;
    }
    __shared__ float ls[2][HID], ls2[2][HID];
    ls[half][f] = s;
    ls2[half][f] = s2;
    __syncthreads();
    if (half == 0) {
        atomicAdd(&stats[f], ls[0][f] + ls[1][f]);
        atomicAdd(&stats[HID + f], ls2[0][f] + ls2[1][f]);
    }
}

__global__ void k_bnfinal(float* __restrict__ stats, const float* __restrict__ gamma,
                          const float* __restrict__ beta, float n) {
    int j = threadIdx.x;
    if (j < HID) {
        float mu = stats[j] / n;
        float var = stats[HID + j] / n - mu * mu;
        float sc = gamma[j] * rsqrtf(var + BN_EPS);
        stats[256 + j] = sc;
        stats[384 + j] = beta[j] - mu * sc;
    }
}

__global__ __launch_bounds__(256) void k_pool(const float* __restrict__ y,
                                              const float* __restrict__ stats,
                                              const int* __restrict__ batch,
                                              float* __restrict__ gsum,
                                              float* __restrict__ gcnt, int N) {
    int half = threadIdx.x >> 7, f = threadIdx.x & 127;
    int n = blockIdx.x * 2 + half;
    if (n >= N) return;
    float v = y[n * HID + f] * stats[256 + f] + stats[384 + f];
    v = fmaxf(v, 0.f);
    int g = batch[n];
    atomicAdd(&gsum[g * HID + f], v);
    if (f == 0) atomicAdd(&gcnt[g], 1.0f);
}

__global__ void k_head(const float* __restrict__ gsum, const float* __restrict__ gcnt,
                       const float* __restrict__ w2, const float* __restrict__ b2,
                       float* __restrict__ out) {
    int g = blockIdx.x * blockDim.x + threadIdx.x;
    if (g >= NGRAPHS) return;
    float inv = 1.0f / fmaxf(gcnt[g], 1.0f);
    float logits[NCLASSES];
    float mx = -1e30f;
    for (int c = 0; c < NCLASSES; ++c) {
        float acc = b2[c];
        for (int f = 0; f < HID; ++f) acc += gsum[g * HID + f] * inv * w2[c * HID + f];
        logits[c] = acc;
        mx = fmaxf(mx, acc);
    }
    float se = 0.f;
    for (int c = 0; c < NCLASSES; ++c) se += expf(logits[c] - mx);
    float lse = mx + logf(se);
    for (int c = 0; c < NCLASSES; ++c) out[g * NCLASSES + c] = logits[c] - lse;
}

// ---------------- launch ----------------

extern "C" void kernel_launch(void* const* d_in, const int* in_sizes, int n_in,
                              void* d_out, int out_size, void* d_ws, size_t ws_size,
                              hipStream_t stream) {
    const float* x     = (const float*)d_in[0];
    const int*   ei    = (const int*)d_in[1];
    const int*   batch = (const int*)d_in[2];
    const float* ggnnw = (const float*)d_in[3];
    const float* w_ih  = (const float*)d_in[4];
    const float* w_hh  = (const float*)d_in[5];
    const float* b_ih  = (const float*)d_in[6];
    const float* b_hh  = (const float*)d_in[7];
    const float* fc1_w = (const float*)d_in[8];
    // d_in[9] fc1_b: cancels exactly in training-mode BN -> unused
    const float* gamma = (const float*)d_in[10];
    const float* beta  = (const float*)d_in[11];
    const float* fc2_w = (const float*)d_in[12];
    const float* fc2_b = (const float*)d_in[13];
    float* out = (float*)d_out;

    const int N = in_sizes[0] / HID; // 100000
    const int E = in_sizes[1] / 2;   // 1600000

    char* w = (char*)d_ws;
    auto alloc = [&](size_t bytes) -> char* {
        char* p = w;
        w += (bytes + 255) & ~(size_t)255;
        return p;
    };
    float* h    = (float*)alloc(sizeof(float) * (size_t)N * HID);
    float* m    = (float*)alloc(sizeof(float) * (size_t)N * HID); // also y after layers
    float* agg  = (float*)alloc(sizeof(float) * (size_t)N * HID);
    float* wiT  = (float*)alloc(sizeof(float) * 384 * HID);
    float* whT  = (float*)alloc(sizeof(float) * 384 * HID);
    float* f1T  = (float*)alloc(sizeof(float) * HID * HID);
    int* rowstart = (int*)alloc(sizeof(int) * (N + 4));
    int* colb     = (int*)alloc(sizeof(int) * E);
    int* bsum     = (int*)alloc(sizeof(int) * 512);
    int* boff     = (int*)alloc(sizeof(int) * 512);
    // zero-initialized region (one memset): deg, cursor, stats, gsum, gcnt
    size_t zelems = (size_t)N + N + 512 + NGRAPHS * HID + 256;
    char* zbase = alloc(zelems * 4);
    int*   deg    = (int*)zbase;
    int*   cursor = deg + N;
    float* stats  = (float*)(cursor + N); // [0:128) sum, [128:256) sumsq, [256:384) scale, [384:512) shift
    float* gsum   = stats + 512;
    float* gcnt   = gsum + NGRAPHS * HID;

    hipMemsetAsync(zbase, 0, zelems * 4, stream);
    hipMemcpyAsync(h, x, sizeof(float) * (size_t)N * HID, hipMemcpyDeviceToDevice, stream);

    k_transpose<<<(384 * HID + 255) / 256, 256, 0, stream>>>(w_ih, wiT, 384, HID);
    k_transpose<<<(384 * HID + 255) / 256, 256, 0, stream>>>(w_hh, whT, 384, HID);
    k_transpose<<<(HID * HID + 255) / 256, 256, 0, stream>>>(fc1_w, f1T, HID, HID);

    // build CSR (dst -> list of src)
    int nb1 = (N + 255) / 256;
    k_deg<<<(E + 255) / 256, 256, 0, stream>>>(ei, E, deg);
    k_scan1<<<nb1, 256, 0, stream>>>(deg, N, rowstart, bsum);
    k_scan2<<<1, 512, 0, stream>>>(bsum, nb1, boff);
    k_scan3<<<nb1, 256, 0, stream>>>(rowstart, boff, N, E);
    k_fill<<<(E + 255) / 256, 256, 0, stream>>>(ei, E, rowstart, cursor, colb);

    int ntiles = (N + 15) / 16;
    for (int l = 0; l < NLAYERS; ++l) {
        k_matmul128<<<ntiles, 128, 0, stream>>>(h, ggnnw + (size_t)l * HID * HID, m, N);
        k_gather<<<(N + 1) / 2, 256, 0, stream>>>(m, rowstart, colb, agg, N);
        k_gru<<<ntiles, 384, 0, stream>>>(agg, h, wiT, whT, b_ih, b_hh, N);
    }

    // head: fc1 (bias skipped, cancels in BN) -> BN -> relu -> mean pool -> fc2 -> log_softmax
    k_matmul128<<<ntiles, 128, 0, stream>>>(h, f1T, m, N);
    k_bnstats<<<256, 256, 0, stream>>>(m, stats, N);
    k_bnfinal<<<1, 128, 0, stream>>>(stats, gamma, beta, (float)N);
    k_pool<<<(N + 1) / 2, 256, 0, stream>>>(m, stats, batch, gsum, gcnt, N);
    k_head<<<1, 256, 0, stream>>>(gsum, gcnt, fc2_w, fc2_b, out);
}

// Round 2
// 1790.285 us; speedup vs baseline: 2.2298x; 2.2298x over previous
//
#include <hip/hip_runtime.h>
#include <math.h>

#define HID 128
#define NLAYERS 4
#define NGRAPHS 200
#define NCLASSES 10
#define BN_EPS 1e-5f

typedef short bf16x8 __attribute__((ext_vector_type(8)));
typedef float f32x4 __attribute__((ext_vector_type(4)));

__device__ __forceinline__ ushort f2bf(float f) {
    unsigned u = __float_as_uint(f);
    u = (u + 0x7fffu + ((u >> 16) & 1u)) >> 16;
    return (ushort)u;
}
__device__ __forceinline__ float bf2f(unsigned us) { return __uint_as_float(us << 16); }

// ---------------- prep kernels ----------------

// h fp32 master = x; A[:,128:256] = bf16(x)
__global__ void k_init_x(const float* __restrict__ x, float* __restrict__ h,
                         ushort* __restrict__ A, int N) {
    int idx = blockIdx.x * blockDim.x + threadIdx.x;
    if (idx < N * HID) {
        int n = idx >> 7, c = idx & 127;
        float v = x[idx];
        h[idx] = v;
        A[n * 256 + 128 + c] = f2bf(v);
    }
}

// Combined GRU weight matrix Bc[512][256] (o-major, k contiguous), bf16.
// o in [0,256):   k<128 -> w_ih[o][k],        k>=128 -> w_hh[o][k-128]   (r,z: K=256 over [agg|h])
// o in [256,384): k<128 -> w_ih[o][k],        else 0                     (i_n over agg)
// o in [384,512): k<128 -> 0,                 else w_hh[o-128][k-128]    (h_n over h)
__global__ void k_build_Bc(const float* __restrict__ w_ih, const float* __restrict__ w_hh,
                           ushort* __restrict__ Bc) {
    int idx = blockIdx.x * blockDim.x + threadIdx.x;
    if (idx >= 512 * 256) return;
    int o = idx >> 8, k = idx & 255;
    float v;
    if (o < 256)      v = (k < 128) ? w_ih[o * 128 + k] : w_hh[o * 128 + (k - 128)];
    else if (o < 384) v = (k < 128) ? w_ih[o * 128 + k] : 0.f;
    else              v = (k < 128) ? 0.f : w_hh[(o - 128) * 128 + (k - 128)];
    Bc[idx] = f2bf(v);
}

// folded biases for the 512 combined columns
__global__ void k_bias(const float* __restrict__ b_ih, const float* __restrict__ b_hh,
                       float* __restrict__ bias) {
    int j = threadIdx.x;
    if (j >= 512) return;
    float v;
    if (j < 256)      v = b_ih[j] + b_hh[j];
    else if (j < 384) v = b_ih[j];
    else              v = b_hh[j - 128];
    bias[j] = v;
}

// ggnn_weight[l][k][o] -> Bg[l][o][k] bf16 (o-major, k contiguous)
__global__ void k_cvt_bg(const float* __restrict__ w, ushort* __restrict__ Bg) {
    int idx = blockIdx.x * blockDim.x + threadIdx.x;
    if (idx >= NLAYERS * HID * HID) return;
    int l = idx >> 14, rem = idx & 16383;
    int k = rem >> 7, o = rem & 127;
    Bg[(l << 14) + o * 128 + k] = f2bf(w[idx]);
}

// fc1_w is already [o][k] -> straight bf16 convert
__global__ void k_cvt_fc1(const float* __restrict__ w, ushort* __restrict__ B) {
    int idx = blockIdx.x * blockDim.x + threadIdx.x;
    if (idx < HID * HID) B[idx] = f2bf(w[idx]);
}

// ---------------- CSR build ----------------

__global__ void k_deg(const int* __restrict__ ei, int E, int* __restrict__ deg) {
    int e = blockIdx.x * blockDim.x + threadIdx.x;
    if (e < E) atomicAdd(&deg[ei[E + e]], 1);
}

__global__ void k_scan1(const int* __restrict__ deg, int N,
                        int* __restrict__ rowstart, int* __restrict__ bsum) {
    __shared__ int s[256];
    int t = threadIdx.x;
    int i = blockIdx.x * 256 + t;
    int v = (i < N) ? deg[i] : 0;
    s[t] = v;
    __syncthreads();
    for (int off = 1; off < 256; off <<= 1) {
        int a = (t >= off) ? s[t - off] : 0;
        __syncthreads();
        s[t] += a;
        __syncthreads();
    }
    if (i < N) rowstart[i] = s[t] - v;
    if (t == 255) bsum[blockIdx.x] = s[255];
}

__global__ void k_scan2(const int* __restrict__ bsum, int nb, int* __restrict__ boff) {
    __shared__ int s[512];
    int t = threadIdx.x;
    int v = (t < nb) ? bsum[t] : 0;
    s[t] = v;
    __syncthreads();
    for (int off = 1; off < 512; off <<= 1) {
        int a = (t >= off) ? s[t - off] : 0;
        __syncthreads();
        s[t] += a;
        __syncthreads();
    }
    if (t < nb) boff[t] = s[t] - v;
}

__global__ void k_scan3(int* __restrict__ rowstart, const int* __restrict__ boff,
                        int N, int E) {
    int i = blockIdx.x * 256 + threadIdx.x;
    if (i < N) rowstart[i] += boff[blockIdx.x];
    if (i == 0) rowstart[N] = E;
}

__global__ void k_fill(const int* __restrict__ ei, int E,
                       const int* __restrict__ rowstart, int* __restrict__ cursor,
                       int* __restrict__ col) {
    int e = blockIdx.x * blockDim.x + threadIdx.x;
    if (e < E) {
        int d = ei[E + e];
        int pos = atomicAdd(&cursor[d], 1);
        col[rowstart[d] + pos] = ei[e];
    }
}

// ---------------- MFMA GEMM: out[P,128] = Ain(bf16, stride astride)@B[128o][128k] ------
// M-tile 64, block 256 threads (4 waves). Wave w owns cols [32w,32w+32).
// Output bf16 to mo if mo!=null, else fp32 to yo.

__global__ __launch_bounds__(256, 3) void k_mm_mfma(
    const ushort* __restrict__ Ain, int astride, const ushort* __restrict__ B,
    ushort* __restrict__ mo, float* __restrict__ yo) {
    int w = threadIdx.x >> 6, lane = threadIdx.x & 63;
    int quad = lane >> 4, tn = lane & 15;
    int rowb = blockIdx.x << 6;
    f32x4 acc[4][2];
#pragma unroll
    for (int rt = 0; rt < 4; ++rt)
#pragma unroll
        for (int c2 = 0; c2 < 2; ++c2) acc[rt][c2] = (f32x4){0.f, 0.f, 0.f, 0.f};
    for (int ks = 0; ks < 4; ++ks) {
        int k0 = ks * 32 + quad * 8;
        bf16x8 af[4];
#pragma unroll
        for (int rt = 0; rt < 4; ++rt)
            af[rt] = *(const bf16x8*)(Ain + (rowb + rt * 16 + tn) * astride + k0);
        bf16x8 bfr[2];
#pragma unroll
        for (int c2 = 0; c2 < 2; ++c2)
            bfr[c2] = *(const bf16x8*)(B + (w * 32 + c2 * 16 + tn) * 128 + k0);
#pragma unroll
        for (int rt = 0; rt < 4; ++rt)
#pragma unroll
            for (int c2 = 0; c2 < 2; ++c2)
                acc[rt][c2] = __builtin_amdgcn_mfma_f32_16x16x32_bf16(
                    af[rt], bfr[c2], acc[rt][c2], 0, 0, 0);
    }
#pragma unroll
    for (int c2 = 0; c2 < 2; ++c2) {
        int col = w * 32 + c2 * 16 + tn;
#pragma unroll
        for (int rt = 0; rt < 4; ++rt)
#pragma unroll
            for (int r = 0; r < 4; ++r) {
                int row = rowb + rt * 16 + quad * 4 + r;
                if (mo) mo[row * 128 + col] = f2bf(acc[rt][c2][r]);
                else    yo[row * 128 + col] = acc[rt][c2][r];
            }
    }
}

// ---------------- CSR gather (bf16): A[:,0:128] = sum of m rows ----------------

__global__ __launch_bounds__(256) void k_gather_bf(const ushort* __restrict__ m,
                                                   const int* __restrict__ rowstart,
                                                   const int* __restrict__ col,
                                                   ushort* __restrict__ A, int N) {
    int node = blockIdx.x * 4 + (threadIdx.x >> 6);
    int lane = threadIdx.x & 63;
    if (node >= N) return;
    int s = rowstart[node], e = rowstart[node + 1];
    float a0 = 0.f, a1 = 0.f, b0 = 0.f, b1 = 0.f;
    int i = s;
    for (; i + 1 < e; i += 2) {
        int c0 = col[i], c1 = col[i + 1];
        unsigned v0 = *(const unsigned*)(m + c0 * 128 + 2 * lane);
        unsigned v1 = *(const unsigned*)(m + c1 * 128 + 2 * lane);
        a0 += bf2f(v0 & 0xffffu);
        a1 += bf2f(v0 >> 16);
        b0 += bf2f(v1 & 0xffffu);
        b1 += bf2f(v1 >> 16);
    }
    if (i < e) {
        unsigned v0 = *(const unsigned*)(m + col[i] * 128 + 2 * lane);
        a0 += bf2f(v0 & 0xffffu);
        a1 += bf2f(v0 >> 16);
    }
    unsigned pack = (unsigned)f2bf(a0 + b0) | ((unsigned)f2bf(a1 + b1) << 16);
    *(unsigned*)(A + node * 256 + 2 * lane) = pack;
}

// ---------------- fused GRU GEMM: C[P,512] = A[P,256]@Bc^T, gates in epilogue --------
// M-tile 64, 4 waves. Wave w owns cols [32w,32w+32) of EACH gate group g (0..3),
// so gate math is pure-register: matching (reg,lane) positions across groups.

__global__ __launch_bounds__(256, 2) void k_gru_mfma(
    const ushort* __restrict__ A, const ushort* __restrict__ Bc,
    const float* __restrict__ bias, float* __restrict__ h, ushort* Ah) {
    int w = threadIdx.x >> 6, lane = threadIdx.x & 63;
    int quad = lane >> 4, tn = lane & 15;
    int rowb = blockIdx.x << 6;
    f32x4 acc[4][4][2]; // [row-tile][gate-group][col-half]
#pragma unroll
    for (int rt = 0; rt < 4; ++rt)
#pragma unroll
        for (int g = 0; g < 4; ++g)
#pragma unroll
            for (int c2 = 0; c2 < 2; ++c2) acc[rt][g][c2] = (f32x4){0.f, 0.f, 0.f, 0.f};
    for (int ks = 0; ks < 8; ++ks) {
        int k0 = ks * 32 + quad * 8;
        bf16x8 af[4];
#pragma unroll
        for (int rt = 0; rt < 4; ++rt)
            af[rt] = *(const bf16x8*)(A + (rowb + rt * 16 + tn) * 256 + k0);
        bf16x8 bfr[4][2];
#pragma unroll
        for (int g = 0; g < 4; ++g)
#pragma unroll
            for (int c2 = 0; c2 < 2; ++c2) {
                int o = g * 128 + w * 32 + c2 * 16 + tn;
                bfr[g][c2] = *(const bf16x8*)(Bc + o * 256 + k0);
            }
#pragma unroll
        for (int rt = 0; rt < 4; ++rt)
#pragma unroll
            for (int g = 0; g < 4; ++g)
#pragma unroll
                for (int c2 = 0; c2 < 2; ++c2)
                    acc[rt][g][c2] = __builtin_amdgcn_mfma_f32_16x16x32_bf16(
                        af[rt], bfr[g][c2], acc[rt][g][c2], 0, 0, 0);
    }
#pragma unroll
    for (int c2 = 0; c2 < 2; ++c2) {
        int cc = w * 32 + c2 * 16 + tn; // gate column 0..127
        float br = bias[cc], bz = bias[128 + cc], bin = bias[256 + cc], bhn = bias[384 + cc];
#pragma unroll
        for (int rt = 0; rt < 4; ++rt)
#pragma unroll
            for (int r = 0; r < 4; ++r) {
                int row = rowb + rt * 16 + quad * 4 + r;
                float ur = acc[rt][0][c2][r] + br;
                float uz = acc[rt][1][c2][r] + bz;
                float xin = acc[rt][2][c2][r] + bin;
                float xhn = acc[rt][3][c2][r] + bhn;
                float rr = 1.f / (1.f + __expf(-ur));
                float zz = 1.f / (1.f + __expf(-uz));
                float nn = tanhf(xin + rr * xhn);
                float ho = h[row * 128 + cc];
                float hv = (1.f - zz) * nn + zz * ho;
                h[row * 128 + cc] = hv;
                Ah[row * 256 + cc] = f2bf(hv); // bf16 copy into A's h-half
            }
    }
}

// ---------------- BN stats / finalize / pool / head (y is bf16 in m buffer) ----------

__global__ __launch_bounds__(256) void k_bnstats(const ushort* __restrict__ y,
                                                 float* __restrict__ stats, int N) {
    int half = threadIdx.x >> 7, f = threadIdx.x & 127;
    float s = 0.f, s2 = 0.f;
    for (int n = blockIdx.x * 2 + half; n < N; n += gridDim.x * 2) {
        float v = bf2f(y[n * HID + f]);
        s += v;
        s2 += v * v;
    }
    __shared__ float ls[2][HID], ls2[2][HID];
    ls[half][f] = s;
    ls2[half][f] = s2;
    __syncthreads();
    if (half == 0) {
        atomicAdd(&stats[f], ls[0][f] + ls[1][f]);
        atomicAdd(&stats[HID + f], ls2[0][f] + ls2[1][f]);
    }
}

__global__ void k_bnfinal(float* __restrict__ stats, const float* __restrict__ gamma,
                          const float* __restrict__ beta, float n) {
    int j = threadIdx.x;
    if (j < HID) {
        float mu = stats[j] / n;
        float var = stats[HID + j] / n - mu * mu;
        float sc = gamma[j] * rsqrtf(var + BN_EPS);
        stats[256 + j] = sc;
        stats[384 + j] = beta[j] - mu * sc;
    }
}

__global__ __launch_bounds__(256) void k_pool(const ushort* __restrict__ y,
                                              const float* __restrict__ stats,
                                              const int* __restrict__ batch,
                                              float* __restrict__ gsum,
                                              float* __restrict__ gcnt, int N) {
    int half = threadIdx.x >> 7, f = threadIdx.x & 127;
    int n = blockIdx.x * 2 + half;
    if (n >= N) return;
    float v = bf2f(y[n * HID + f]) * stats[256 + f] + stats[384 + f];
    v = fmaxf(v, 0.f);
    int g = batch[n];
    atomicAdd(&gsum[g * HID + f], v);
    if (f == 0) atomicAdd(&gcnt[g], 1.0f);
}

__global__ void k_head(const float* __restrict__ gsum, const float* __restrict__ gcnt,
                       const float* __restrict__ w2, const float* __restrict__ b2,
                       float* __restrict__ out) {
    int g = blockIdx.x * blockDim.x + threadIdx.x;
    if (g >= NGRAPHS) return;
    float inv = 1.0f / fmaxf(gcnt[g], 1.0f);
    float logits[NCLASSES];
    float mx = -1e30f;
    for (int c = 0; c < NCLASSES; ++c) {
        float acc = b2[c];
        for (int f = 0; f < HID; ++f) acc += gsum[g * HID + f] * inv * w2[c * HID + f];
        logits[c] = acc;
        mx = fmaxf(mx, acc);
    }
    float se = 0.f;
    for (int c = 0; c < NCLASSES; ++c) se += expf(logits[c] - mx);
    float lse = mx + logf(se);
    for (int c = 0; c < NCLASSES; ++c) out[g * NCLASSES + c] = logits[c] - lse;
}

// ---------------- launch ----------------

extern "C" void kernel_launch(void* const* d_in, const int* in_sizes, int n_in,
                              void* d_out, int out_size, void* d_ws, size_t ws_size,
                              hipStream_t stream) {
    const float* x     = (const float*)d_in[0];
    const int*   ei    = (const int*)d_in[1];
    const int*   batch = (const int*)d_in[2];
    const float* ggnnw = (const float*)d_in[3];
    const float* w_ih  = (const float*)d_in[4];
    const float* w_hh  = (const float*)d_in[5];
    const float* b_ih  = (const float*)d_in[6];
    const float* b_hh  = (const float*)d_in[7];
    const float* fc1_w = (const float*)d_in[8];
    // d_in[9] fc1_b: cancels exactly in training-mode BN -> unused
    const float* gamma = (const float*)d_in[10];
    const float* beta  = (const float*)d_in[11];
    const float* fc2_w = (const float*)d_in[12];
    const float* fc2_b = (const float*)d_in[13];
    float* out = (float*)d_out;

    const int N = in_sizes[0] / HID; // 100000
    const int E = in_sizes[1] / 2;   // 1600000
    const int nblk64 = (N + 63) / 64;
    const int P = nblk64 * 64; // padded rows

    char* w = (char*)d_ws;
    auto alloc = [&](size_t bytes) -> char* {
        char* p = w;
        w += (bytes + 255) & ~(size_t)255;
        return p;
    };
    float*  h   = (float*)alloc(sizeof(float) * (size_t)P * HID);
    ushort* A   = (ushort*)alloc(sizeof(ushort) * (size_t)P * 256); // [agg | h] bf16
    ushort* m   = (ushort*)alloc(sizeof(ushort) * (size_t)P * HID); // messages; y at head
    ushort* Bc  = (ushort*)alloc(sizeof(ushort) * 512 * 256);
    ushort* Bg  = (ushort*)alloc(sizeof(ushort) * NLAYERS * HID * HID);
    ushort* f1b = (ushort*)alloc(sizeof(ushort) * HID * HID);
    float*  bias = (float*)alloc(sizeof(float) * 512);
    int* rowstart = (int*)alloc(sizeof(int) * (N + 4));
    int* colb     = (int*)alloc(sizeof(int) * E);
    int* bsum     = (int*)alloc(sizeof(int) * 512);
    int* boff     = (int*)alloc(sizeof(int) * 512);
    size_t zelems = (size_t)N + N + 512 + NGRAPHS * HID + 256;
    char* zbase = alloc(zelems * 4);
    int*   deg    = (int*)zbase;
    int*   cursor = deg + N;
    float* stats  = (float*)(cursor + N);
    float* gsum   = stats + 512;
    float* gcnt   = gsum + NGRAPHS * HID;

    hipMemsetAsync(zbase, 0, zelems * 4, stream);

    k_init_x<<<(N * HID + 255) / 256, 256, 0, stream>>>(x, h, A, N);
    k_build_Bc<<<(512 * 256 + 255) / 256, 256, 0, stream>>>(w_ih, w_hh, Bc);
    k_bias<<<1, 512, 0, stream>>>(b_ih, b_hh, bias);
    k_cvt_bg<<<(NLAYERS * HID * HID + 255) / 256, 256, 0, stream>>>(ggnnw, Bg);
    k_cvt_fc1<<<(HID * HID + 255) / 256, 256, 0, stream>>>(fc1_w, f1b);

    int nb1 = (N + 255) / 256;
    k_deg<<<(E + 255) / 256, 256, 0, stream>>>(ei, E, deg);
    k_scan1<<<nb1, 256, 0, stream>>>(deg, N, rowstart, bsum);
    k_scan2<<<1, 512, 0, stream>>>(bsum, nb1, boff);
    k_scan3<<<nb1, 256, 0, stream>>>(rowstart, boff, N, E);
    k_fill<<<(E + 255) / 256, 256, 0, stream>>>(ei, E, rowstart, cursor, colb);

    for (int l = 0; l < NLAYERS; ++l) {
        k_mm_mfma<<<nblk64, 256, 0, stream>>>(A + 128, 256, Bg + (size_t)l * HID * HID,
                                              m, nullptr);
        k_gather_bf<<<(N + 3) / 4, 256, 0, stream>>>(m, rowstart, colb, A, N);
        k_gru_mfma<<<nblk64, 256, 0, stream>>>(A, Bc, bias, h, A + 128);
    }

    // head: fc1 (bf16, bias cancels in BN) -> BN -> relu -> pool -> fc2 -> log_softmax
    k_mm_mfma<<<nblk64, 256, 0, stream>>>(A + 128, 256, f1b, m, nullptr);
    k_bnstats<<<256, 256, 0, stream>>>(m, stats, N);
    k_bnfinal<<<1, 128, 0, stream>>>(stats, gamma, beta, (float)N);
    k_pool<<<(N + 1) / 2, 256, 0, stream>>>(m, stats, batch, gsum, gcnt, N);
    k_head<<<1, 256, 0, stream>>>(gsum, gcnt, fc2_w, fc2_b, out);
}

// Round 3
// 1417.307 us; speedup vs baseline: 2.8166x; 1.2632x over previous
//
#include <hip/hip_runtime.h>
#include <math.h>

#define HID 128
#define NLAYERS 4
#define NGRAPHS 200
#define NCLASSES 10
#define BN_EPS 1e-5f

typedef short bf16x8 __attribute__((ext_vector_type(8)));
typedef float f32x4 __attribute__((ext_vector_type(4)));

__device__ __forceinline__ ushort f2bf(float f) {
    unsigned u = __float_as_uint(f);
    u = (u + 0x7fffu + ((u >> 16) & 1u)) >> 16;
    return (ushort)u;
}
__device__ __forceinline__ float bf2f(unsigned us) { return __uint_as_float(us << 16); }

// ---------------- prep kernels ----------------

// h fp32 master = x; A[:,128:256] = bf16(x)
__global__ void k_init_x(const float* __restrict__ x, float* __restrict__ h,
                         ushort* __restrict__ A, int N) {
    int idx = blockIdx.x * blockDim.x + threadIdx.x;
    if (idx < N * HID) {
        int n = idx >> 7, c = idx & 127;
        float v = x[idx];
        h[idx] = v;
        A[n * 256 + 128 + c] = f2bf(v);
    }
}

// Combined GRU weight matrix Bc[512][256] (o-major, k contiguous), bf16.
__global__ void k_build_Bc(const float* __restrict__ w_ih, const float* __restrict__ w_hh,
                           ushort* __restrict__ Bc) {
    int idx = blockIdx.x * blockDim.x + threadIdx.x;
    if (idx >= 512 * 256) return;
    int o = idx >> 8, k = idx & 255;
    float v;
    if (o < 256)      v = (k < 128) ? w_ih[o * 128 + k] : w_hh[o * 128 + (k - 128)];
    else if (o < 384) v = (k < 128) ? w_ih[o * 128 + k] : 0.f;
    else              v = (k < 128) ? 0.f : w_hh[(o - 128) * 128 + (k - 128)];
    Bc[idx] = f2bf(v);
}

__global__ void k_bias(const float* __restrict__ b_ih, const float* __restrict__ b_hh,
                       float* __restrict__ bias) {
    int j = threadIdx.x;
    if (j >= 512) return;
    float v;
    if (j < 256)      v = b_ih[j] + b_hh[j];
    else if (j < 384) v = b_ih[j];
    else              v = b_hh[j - 128];
    bias[j] = v;
}

// ggnn_weight[l][k][o] -> Bg[l][o][k] bf16 (o-major, k contiguous)
__global__ void k_cvt_bg(const float* __restrict__ w, ushort* __restrict__ Bg) {
    int idx = blockIdx.x * blockDim.x + threadIdx.x;
    if (idx >= NLAYERS * HID * HID) return;
    int l = idx >> 14, rem = idx & 16383;
    int k = rem >> 7, o = rem & 127;
    Bg[(l << 14) + o * 128 + k] = f2bf(w[idx]);
}

__global__ void k_cvt_fc1(const float* __restrict__ w, ushort* __restrict__ B) {
    int idx = blockIdx.x * blockDim.x + threadIdx.x;
    if (idx < HID * HID) B[idx] = f2bf(w[idx]);
}

// ---------------- CSR build ----------------

__global__ void k_deg(const int* __restrict__ ei, int E, int* __restrict__ deg) {
    int e = blockIdx.x * blockDim.x + threadIdx.x;
    if (e < E) atomicAdd(&deg[ei[E + e]], 1);
}

__global__ void k_scan1(const int* __restrict__ deg, int N,
                        int* __restrict__ rowstart, int* __restrict__ bsum) {
    __shared__ int s[256];
    int t = threadIdx.x;
    int i = blockIdx.x * 256 + t;
    int v = (i < N) ? deg[i] : 0;
    s[t] = v;
    __syncthreads();
    for (int off = 1; off < 256; off <<= 1) {
        int a = (t >= off) ? s[t - off] : 0;
        __syncthreads();
        s[t] += a;
        __syncthreads();
    }
    if (i < N) rowstart[i] = s[t] - v;
    if (t == 255) bsum[blockIdx.x] = s[255];
}

__global__ void k_scan2(const int* __restrict__ bsum, int nb, int* __restrict__ boff) {
    __shared__ int s[512];
    int t = threadIdx.x;
    int v = (t < nb) ? bsum[t] : 0;
    s[t] = v;
    __syncthreads();
    for (int off = 1; off < 512; off <<= 1) {
        int a = (t >= off) ? s[t - off] : 0;
        __syncthreads();
        s[t] += a;
        __syncthreads();
    }
    if (t < nb) boff[t] = s[t] - v;
}

__global__ void k_scan3(int* __restrict__ rowstart, const int* __restrict__ boff,
                        int N, int E) {
    int i = blockIdx.x * 256 + threadIdx.x;
    if (i < N) rowstart[i] += boff[blockIdx.x];
    if (i == 0) rowstart[N] = E;
}

__global__ void k_fill(const int* __restrict__ ei, int E,
                       const int* __restrict__ rowstart, int* __restrict__ cursor,
                       int* __restrict__ col) {
    int e = blockIdx.x * blockDim.x + threadIdx.x;
    if (e < E) {
        int d = ei[E + e];
        int pos = atomicAdd(&cursor[d], 1);
        col[rowstart[d] + pos] = ei[e];
    }
}

// ---------------- MFMA GEMM: out[P,128] = Ain(bf16, stride astride)@B[128o][128k] ------

__global__ __launch_bounds__(256, 3) void k_mm_mfma(
    const ushort* __restrict__ Ain, int astride, const ushort* __restrict__ B,
    ushort* __restrict__ mo, float* __restrict__ yo) {
    int w = threadIdx.x >> 6, lane = threadIdx.x & 63;
    int quad = lane >> 4, tn = lane & 15;
    int rowb = blockIdx.x << 6;
    f32x4 acc[4][2];
#pragma unroll
    for (int rt = 0; rt < 4; ++rt)
#pragma unroll
        for (int c2 = 0; c2 < 2; ++c2) acc[rt][c2] = (f32x4){0.f, 0.f, 0.f, 0.f};
    for (int ks = 0; ks < 4; ++ks) {
        int k0 = ks * 32 + quad * 8;
        bf16x8 af[4];
#pragma unroll
        for (int rt = 0; rt < 4; ++rt)
            af[rt] = *(const bf16x8*)(Ain + (rowb + rt * 16 + tn) * astride + k0);
        bf16x8 bfr[2];
#pragma unroll
        for (int c2 = 0; c2 < 2; ++c2)
            bfr[c2] = *(const bf16x8*)(B + (w * 32 + c2 * 16 + tn) * 128 + k0);
#pragma unroll
        for (int rt = 0; rt < 4; ++rt)
#pragma unroll
            for (int c2 = 0; c2 < 2; ++c2)
                acc[rt][c2] = __builtin_amdgcn_mfma_f32_16x16x32_bf16(
                    af[rt], bfr[c2], acc[rt][c2], 0, 0, 0);
    }
#pragma unroll
    for (int c2 = 0; c2 < 2; ++c2) {
        int col = w * 32 + c2 * 16 + tn;
#pragma unroll
        for (int rt = 0; rt < 4; ++rt)
#pragma unroll
            for (int r = 0; r < 4; ++r) {
                int row = rowb + rt * 16 + quad * 4 + r;
                if (mo) mo[row * 128 + col] = f2bf(acc[rt][c2][r]);
                else    yo[row * 128 + col] = acc[rt][c2][r];
            }
    }
}

// ---------------- CSR gather (bf16): A[:,0:128] = sum of m rows ----------------

__global__ __launch_bounds__(256) void k_gather_bf(const ushort* __restrict__ m,
                                                   const int* __restrict__ rowstart,
                                                   const int* __restrict__ col,
                                                   ushort* __restrict__ A, int N) {
    int node = blockIdx.x * 4 + (threadIdx.x >> 6);
    int lane = threadIdx.x & 63;
    if (node >= N) return;
    int s = rowstart[node], e = rowstart[node + 1];
    float a0 = 0.f, a1 = 0.f, b0 = 0.f, b1 = 0.f;
    int i = s;
    for (; i + 1 < e; i += 2) {
        int c0 = col[i], c1 = col[i + 1];
        unsigned v0 = *(const unsigned*)(m + c0 * 128 + 2 * lane);
        unsigned v1 = *(const unsigned*)(m + c1 * 128 + 2 * lane);
        a0 += bf2f(v0 & 0xffffu);
        a1 += bf2f(v0 >> 16);
        b0 += bf2f(v1 & 0xffffu);
        b1 += bf2f(v1 >> 16);
    }
    if (i < e) {
        unsigned v0 = *(const unsigned*)(m + col[i] * 128 + 2 * lane);
        a0 += bf2f(v0 & 0xffffu);
        a1 += bf2f(v0 >> 16);
    }
    unsigned pack = (unsigned)f2bf(a0 + b0) | ((unsigned)f2bf(a1 + b1) << 16);
    *(unsigned*)(A + node * 256 + 2 * lane) = pack;
}

// ---------------- fused GRU GEMM ----------------

__global__ __launch_bounds__(256, 2) void k_gru_mfma(
    const ushort* __restrict__ A, const ushort* __restrict__ Bc,
    const float* __restrict__ bias, float* __restrict__ h, ushort* Ah) {
    int w = threadIdx.x >> 6, lane = threadIdx.x & 63;
    int quad = lane >> 4, tn = lane & 15;
    int rowb = blockIdx.x << 6;
    f32x4 acc[4][4][2];
#pragma unroll
    for (int rt = 0; rt < 4; ++rt)
#pragma unroll
        for (int g = 0; g < 4; ++g)
#pragma unroll
            for (int c2 = 0; c2 < 2; ++c2) acc[rt][g][c2] = (f32x4){0.f, 0.f, 0.f, 0.f};
    for (int ks = 0; ks < 8; ++ks) {
        int k0 = ks * 32 + quad * 8;
        bf16x8 af[4];
#pragma unroll
        for (int rt = 0; rt < 4; ++rt)
            af[rt] = *(const bf16x8*)(A + (rowb + rt * 16 + tn) * 256 + k0);
        bf16x8 bfr[4][2];
#pragma unroll
        for (int g = 0; g < 4; ++g)
#pragma unroll
            for (int c2 = 0; c2 < 2; ++c2) {
                int o = g * 128 + w * 32 + c2 * 16 + tn;
                bfr[g][c2] = *(const bf16x8*)(Bc + o * 256 + k0);
            }
#pragma unroll
        for (int rt = 0; rt < 4; ++rt)
#pragma unroll
            for (int g = 0; g < 4; ++g)
#pragma unroll
                for (int c2 = 0; c2 < 2; ++c2)
                    acc[rt][g][c2] = __builtin_amdgcn_mfma_f32_16x16x32_bf16(
                        af[rt], bfr[g][c2], acc[rt][g][c2], 0, 0, 0);
    }
#pragma unroll
    for (int c2 = 0; c2 < 2; ++c2) {
        int cc = w * 32 + c2 * 16 + tn;
        float br = bias[cc], bz = bias[128 + cc], bin = bias[256 + cc], bhn = bias[384 + cc];
#pragma unroll
        for (int rt = 0; rt < 4; ++rt)
#pragma unroll
            for (int r = 0; r < 4; ++r) {
                int row = rowb + rt * 16 + quad * 4 + r;
                float ur = acc[rt][0][c2][r] + br;
                float uz = acc[rt][1][c2][r] + bz;
                float xin = acc[rt][2][c2][r] + bin;
                float xhn = acc[rt][3][c2][r] + bhn;
                float rr = 1.f / (1.f + __expf(-ur));
                float zz = 1.f / (1.f + __expf(-uz));
                float nn = tanhf(xin + rr * xhn);
                float ho = h[row * 128 + cc];
                float hv = (1.f - zz) * nn + zz * ho;
                h[row * 128 + cc] = hv;
                Ah[row * 256 + cc] = f2bf(hv);
            }
    }
}

// ---------------- BN stats / finalize / pool / head ----------------

__global__ __launch_bounds__(256) void k_bnstats(const ushort* __restrict__ y,
                                                 float* __restrict__ stats, int N) {
    int half = threadIdx.x >> 7, f = threadIdx.x & 127;
    float s = 0.f, s2 = 0.f;
    for (int n = blockIdx.x * 2 + half; n < N; n += gridDim.x * 2) {
        float v = bf2f(y[n * HID + f]);
        s += v;
        s2 += v * v;
    }
    __shared__ float ls[2][HID], ls2[2][HID];
    ls[half][f] = s;
    ls2[half][f] = s2;
    __syncthreads();
    if (half == 0) {
        atomicAdd(&stats[f], ls[0][f] + ls[1][f]);
        atomicAdd(&stats[HID + f], ls2[0][f] + ls2[1][f]);
    }
}

__global__ void k_bnfinal(float* __restrict__ stats, const float* __restrict__ gamma,
                          const float* __restrict__ beta, float n) {
    int j = threadIdx.x;
    if (j < HID) {
        float mu = stats[j] / n;
        float var = stats[HID + j] / n - mu * mu;
        float sc = gamma[j] * rsqrtf(var + BN_EPS);
        stats[256 + j] = sc;
        stats[384 + j] = beta[j] - mu * sc;
    }
}

// batch is SORTED: per-block chunk sweep with register accumulation, flush one
// atomicAdd per (graph,feature) at segment boundaries only.
#define POOL_CHUNK 256
__global__ __launch_bounds__(128) void k_pool(const ushort* __restrict__ y,
                                              const float* __restrict__ stats,
                                              const int* __restrict__ batch,
                                              float* __restrict__ gsum,
                                              float* __restrict__ gcnt, int N) {
    int f = threadIdx.x;
    int start = blockIdx.x * POOL_CHUNK;
    if (start >= N) return;
    int end = min(start + POOL_CHUNK, N);
    float sc = stats[256 + f], sh = stats[384 + f];
    int cur = batch[start];
    float acc = 0.f, cnt = 0.f;
    for (int n = start; n < end; ++n) {
        int g = batch[n];
        if (g != cur) { // wave-uniform branch (batch is per-row scalar)
            atomicAdd(&gsum[cur * HID + f], acc);
            if (f == 0) atomicAdd(&gcnt[cur], cnt);
            acc = 0.f; cnt = 0.f; cur = g;
        }
        float v = bf2f(y[n * HID + f]) * sc + sh;
        acc += fmaxf(v, 0.f);
        cnt += 1.f;
    }
    atomicAdd(&gsum[cur * HID + f], acc);
    if (f == 0) atomicAdd(&gcnt[cur], cnt);
}

__global__ void k_head(const float* __restrict__ gsum, const float* __restrict__ gcnt,
                       const float* __restrict__ w2, const float* __restrict__ b2,
                       float* __restrict__ out) {
    int g = blockIdx.x * blockDim.x + threadIdx.x;
    if (g >= NGRAPHS) return;
    float inv = 1.0f / fmaxf(gcnt[g], 1.0f);
    float logits[NCLASSES];
    float mx = -1e30f;
    for (int c = 0; c < NCLASSES; ++c) {
        float acc = b2[c];
        for (int f = 0; f < HID; ++f) acc += gsum[g * HID + f] * inv * w2[c * HID + f];
        logits[c] = acc;
        mx = fmaxf(mx, acc);
    }
    float se = 0.f;
    for (int c = 0; c < NCLASSES; ++c) se += expf(logits[c] - mx);
    float lse = mx + logf(se);
    for (int c = 0; c < NCLASSES; ++c) out[g * NCLASSES + c] = logits[c] - lse;
}

// ---------------- launch ----------------

extern "C" void kernel_launch(void* const* d_in, const int* in_sizes, int n_in,
                              void* d_out, int out_size, void* d_ws, size_t ws_size,
                              hipStream_t stream) {
    const float* x     = (const float*)d_in[0];
    const int*   ei    = (const int*)d_in[1];
    const int*   batch = (const int*)d_in[2];
    const float* ggnnw = (const float*)d_in[3];
    const float* w_ih  = (const float*)d_in[4];
    const float* w_hh  = (const float*)d_in[5];
    const float* b_ih  = (const float*)d_in[6];
    const float* b_hh  = (const float*)d_in[7];
    const float* fc1_w = (const float*)d_in[8];
    // d_in[9] fc1_b: cancels exactly in training-mode BN -> unused
    const float* gamma = (const float*)d_in[10];
    const float* beta  = (const float*)d_in[11];
    const float* fc2_w = (const float*)d_in[12];
    const float* fc2_b = (const float*)d_in[13];
    float* out = (float*)d_out;

    const int N = in_sizes[0] / HID; // 100000
    const int E = in_sizes[1] / 2;   // 1600000
    const int nblk64 = (N + 63) / 64;
    const int P = nblk64 * 64;

    char* w = (char*)d_ws;
    auto alloc = [&](size_t bytes) -> char* {
        char* p = w;
        w += (bytes + 255) & ~(size_t)255;
        return p;
    };
    float*  h   = (float*)alloc(sizeof(float) * (size_t)P * HID);
    ushort* A   = (ushort*)alloc(sizeof(ushort) * (size_t)P * 256);
    ushort* m   = (ushort*)alloc(sizeof(ushort) * (size_t)P * HID);
    ushort* Bc  = (ushort*)alloc(sizeof(ushort) * 512 * 256);
    ushort* Bg  = (ushort*)alloc(sizeof(ushort) * NLAYERS * HID * HID);
    ushort* f1b = (ushort*)alloc(sizeof(ushort) * HID * HID);
    float*  bias = (float*)alloc(sizeof(float) * 512);
    int* rowstart = (int*)alloc(sizeof(int) * (N + 4));
    int* colb     = (int*)alloc(sizeof(int) * E);
    int* bsum     = (int*)alloc(sizeof(int) * 512);
    int* boff     = (int*)alloc(sizeof(int) * 512);
    size_t zelems = (size_t)N + N + 512 + NGRAPHS * HID + 256;
    char* zbase = alloc(zelems * 4);
    int*   deg    = (int*)zbase;
    int*   cursor = deg + N;
    float* stats  = (float*)(cursor + N);
    float* gsum   = stats + 512;
    float* gcnt   = gsum + NGRAPHS * HID;

    hipMemsetAsync(zbase, 0, zelems * 4, stream);

    k_init_x<<<(N * HID + 255) / 256, 256, 0, stream>>>(x, h, A, N);
    k_build_Bc<<<(512 * 256 + 255) / 256, 256, 0, stream>>>(w_ih, w_hh, Bc);
    k_bias<<<1, 512, 0, stream>>>(b_ih, b_hh, bias);
    k_cvt_bg<<<(NLAYERS * HID * HID + 255) / 256, 256, 0, stream>>>(ggnnw, Bg);
    k_cvt_fc1<<<(HID * HID + 255) / 256, 256, 0, stream>>>(fc1_w, f1b);

    int nb1 = (N + 255) / 256;
    k_deg<<<(E + 255) / 256, 256, 0, stream>>>(ei, E, deg);
    k_scan1<<<nb1, 256, 0, stream>>>(deg, N, rowstart, bsum);
    k_scan2<<<1, 512, 0, stream>>>(bsum, nb1, boff);
    k_scan3<<<nb1, 256, 0, stream>>>(rowstart, boff, N, E);
    k_fill<<<(E + 255) / 256, 256, 0, stream>>>(ei, E, rowstart, cursor, colb);

    for (int l = 0; l < NLAYERS; ++l) {
        k_mm_mfma<<<nblk64, 256, 0, stream>>>(A + 128, 256, Bg + (size_t)l * HID * HID,
                                              m, nullptr);
        k_gather_bf<<<(N + 3) / 4, 256, 0, stream>>>(m, rowstart, colb, A, N);
        k_gru_mfma<<<nblk64, 256, 0, stream>>>(A, Bc, bias, h, A + 128);
    }

    k_mm_mfma<<<nblk64, 256, 0, stream>>>(A + 128, 256, f1b, m, nullptr);
    k_bnstats<<<256, 256, 0, stream>>>(m, stats, N);
    k_bnfinal<<<1, 128, 0, stream>>>(stats, gamma, beta, (float)N);
    k_pool<<<(N + POOL_CHUNK - 1) / POOL_CHUNK, 128, 0, stream>>>(m, stats, batch, gsum, gcnt, N);
    k_head<<<1, 256, 0, stream>>>(gsum, gcnt, fc2_w, fc2_b, out);
}

// Round 4
// 1024.344 us; speedup vs baseline: 3.8971x; 1.3836x over previous
//
#include <hip/hip_runtime.h>
#include <math.h>

#define HID 128
#define NLAYERS 4
#define NGRAPHS 200
#define NCLASSES 10
#define BN_EPS 1e-5f

typedef short bf16x8 __attribute__((ext_vector_type(8)));
typedef float f32x4 __attribute__((ext_vector_type(4)));

__device__ __forceinline__ ushort f2bf(float f) {
    unsigned u = __float_as_uint(f);
    u = (u + 0x7fffu + ((u >> 16) & 1u)) >> 16;
    return (ushort)u;
}
__device__ __forceinline__ float bf2f(unsigned us) { return __uint_as_float(us << 16); }

// ---------------- prep kernels ----------------

// h fp32 master = x; A[:,128:256] = bf16(x)
__global__ void k_init_x(const float* __restrict__ x, float* __restrict__ h,
                         ushort* __restrict__ A, int N) {
    int idx = blockIdx.x * blockDim.x + threadIdx.x;
    if (idx < N * HID) {
        int n = idx >> 7, c = idx & 127;
        float v = x[idx];
        h[idx] = v;
        A[n * 256 + 128 + c] = f2bf(v);
    }
}

// Combined GRU weights in MFMA-fragment order:
// Bc2[((ct*8 + ks)*64 + lane)*8 + j] = Blogical[o=ct*16+(lane&15)][k=ks*32+(lane>>4)*8+j]
// Blogical o in [0,256): r,z over [agg|h]; [256,384): i_n over agg; [384,512): h_n over h.
__global__ void k_build_Bc(const float* __restrict__ w_ih, const float* __restrict__ w_hh,
                           ushort* __restrict__ Bc2) {
    int idx = blockIdx.x * blockDim.x + threadIdx.x;
    if (idx >= 512 * 256) return;
    int j = idx & 7, lane = (idx >> 3) & 63, ks = (idx >> 9) & 7, ct = idx >> 12;
    int o = ct * 16 + (lane & 15);
    int k = ks * 32 + (lane >> 4) * 8 + j;
    float v;
    if (o < 256)      v = (k < 128) ? w_ih[o * 128 + k] : w_hh[o * 128 + (k - 128)];
    else if (o < 384) v = (k < 128) ? w_ih[o * 128 + k] : 0.f;
    else              v = (k < 128) ? 0.f : w_hh[(o - 128) * 128 + (k - 128)];
    Bc2[idx] = f2bf(v);
}

__global__ void k_bias(const float* __restrict__ b_ih, const float* __restrict__ b_hh,
                       float* __restrict__ bias) {
    int j = threadIdx.x;
    if (j >= 512) return;
    float v;
    if (j < 256)      v = b_ih[j] + b_hh[j];
    else if (j < 384) v = b_ih[j];
    else              v = b_hh[j - 128];
    bias[j] = v;
}

// ggnn_weight[l][k][o] -> fragment order (K=128: ks in [0,4), ct in [0,8))
__global__ void k_cvt_bg(const float* __restrict__ w, ushort* __restrict__ Bg2) {
    int idx = blockIdx.x * blockDim.x + threadIdx.x;
    if (idx >= NLAYERS * 16384) return;
    int l = idx >> 14, r = idx & 16383;
    int j = r & 7, lane = (r >> 3) & 63, ks = (r >> 9) & 3, ct = r >> 11;
    int o = ct * 16 + (lane & 15);
    int k = ks * 32 + (lane >> 4) * 8 + j;
    Bg2[idx] = f2bf(w[(l << 14) + k * 128 + o]);
}

// fc1_w[o][k] -> fragment order
__global__ void k_cvt_fc1(const float* __restrict__ w, ushort* __restrict__ B2) {
    int idx = blockIdx.x * blockDim.x + threadIdx.x;
    if (idx >= 16384) return;
    int j = idx & 7, lane = (idx >> 3) & 63, ks = (idx >> 9) & 3, ct = idx >> 11;
    int o = ct * 16 + (lane & 15);
    int k = ks * 32 + (lane >> 4) * 8 + j;
    B2[idx] = f2bf(w[o * 128 + k]);
}

// ---------------- CSR build ----------------

__global__ void k_deg(const int* __restrict__ ei, int E, int* __restrict__ deg) {
    int e = blockIdx.x * blockDim.x + threadIdx.x;
    if (e < E) atomicAdd(&deg[ei[E + e]], 1);
}

__global__ void k_scan1(const int* __restrict__ deg, int N,
                        int* __restrict__ rowstart, int* __restrict__ bsum) {
    __shared__ int s[256];
    int t = threadIdx.x;
    int i = blockIdx.x * 256 + t;
    int v = (i < N) ? deg[i] : 0;
    s[t] = v;
    __syncthreads();
    for (int off = 1; off < 256; off <<= 1) {
        int a = (t >= off) ? s[t - off] : 0;
        __syncthreads();
        s[t] += a;
        __syncthreads();
    }
    if (i < N) rowstart[i] = s[t] - v;
    if (t == 255) bsum[blockIdx.x] = s[255];
}

__global__ void k_scan2(const int* __restrict__ bsum, int nb, int* __restrict__ boff) {
    __shared__ int s[512];
    int t = threadIdx.x;
    int v = (t < nb) ? bsum[t] : 0;
    s[t] = v;
    __syncthreads();
    for (int off = 1; off < 512; off <<= 1) {
        int a = (t >= off) ? s[t - off] : 0;
        __syncthreads();
        s[t] += a;
        __syncthreads();
    }
    if (t < nb) boff[t] = s[t] - v;
}

__global__ void k_scan3(int* __restrict__ rowstart, const int* __restrict__ boff,
                        int N, int E) {
    int i = blockIdx.x * 256 + threadIdx.x;
    if (i < N) rowstart[i] += boff[blockIdx.x];
    if (i == 0) rowstart[N] = E;
}

__global__ void k_fill(const int* __restrict__ ei, int E,
                       const int* __restrict__ rowstart, int* __restrict__ cursor,
                       int* __restrict__ col) {
    int e = blockIdx.x * blockDim.x + threadIdx.x;
    if (e < E) {
        int d = ei[E + e];
        int pos = atomicAdd(&cursor[d], 1);
        col[rowstart[d] + pos] = ei[e];
    }
}

// ---------------- MFMA GEMM: out[P,128] = Ain@B (K=128, B fragment-order) ----------
// LDS-staged A tile, padded stride; B loads are coalesced 1KB wave reads.

#define LDA2 136
__global__ __launch_bounds__(256, 2) void k_mm_mfma(
    const ushort* __restrict__ Ain, int astride, const ushort* __restrict__ B2,
    ushort* __restrict__ mo, float* __restrict__ yo) {
    __shared__ ushort As[64 * LDA2];
    int t = threadIdx.x;
    int rowb = blockIdx.x << 6;
    for (int c = t; c < 1024; c += 256) { // 64 rows x 8 chunks(16B) per row... (128 elems = 16 chunks/row? no: 128*2B/16B = 16) -> 64*16=1024
        int r = c >> 4, off = (c & 15) * 8;
        *(bf16x8*)(As + r * LDA2 + off) =
            *(const bf16x8*)(Ain + (size_t)(rowb + r) * astride + off);
    }
    __syncthreads();
    int w = t >> 6, lane = t & 63;
    int quad = lane >> 4, tn = lane & 15;
    f32x4 acc[4][2];
#pragma unroll
    for (int rt = 0; rt < 4; ++rt)
#pragma unroll
        for (int c2 = 0; c2 < 2; ++c2) acc[rt][c2] = (f32x4){0.f, 0.f, 0.f, 0.f};
    for (int ks = 0; ks < 4; ++ks) {
        int k0 = ks * 32 + quad * 8;
        bf16x8 bfr[2];
#pragma unroll
        for (int c2 = 0; c2 < 2; ++c2) {
            int ct = w * 2 + c2;
            bfr[c2] = *(const bf16x8*)(B2 + (size_t)((ct * 4 + ks) * 64 + lane) * 8);
        }
        bf16x8 af[4];
#pragma unroll
        for (int rt = 0; rt < 4; ++rt)
            af[rt] = *(const bf16x8*)(As + (rt * 16 + tn) * LDA2 + k0);
#pragma unroll
        for (int rt = 0; rt < 4; ++rt)
#pragma unroll
            for (int c2 = 0; c2 < 2; ++c2)
                acc[rt][c2] = __builtin_amdgcn_mfma_f32_16x16x32_bf16(
                    af[rt], bfr[c2], acc[rt][c2], 0, 0, 0);
    }
#pragma unroll
    for (int c2 = 0; c2 < 2; ++c2) {
        int col = w * 32 + c2 * 16 + tn;
#pragma unroll
        for (int rt = 0; rt < 4; ++rt)
#pragma unroll
            for (int r = 0; r < 4; ++r) {
                int row = rowb + rt * 16 + quad * 4 + r;
                if (mo) mo[row * 128 + col] = f2bf(acc[rt][c2][r]);
                else    yo[row * 128 + col] = acc[rt][c2][r];
            }
    }
}

// ---------------- CSR gather (bf16, dwordx4): A[:,0:128] = sum of m rows -----------
// One wave per node; 4 edge-rows in flight (16 lanes x 16B each), unroll 2.

__global__ __launch_bounds__(256) void k_gather_bf(const ushort* __restrict__ m,
                                                   const int* __restrict__ rowstart,
                                                   const int* __restrict__ col,
                                                   ushort* __restrict__ A, int N) {
    int node = blockIdx.x * 4 + (threadIdx.x >> 6);
    int lane = threadIdx.x & 63;
    if (node >= N) return;
    int s = rowstart[node], e = rowstart[node + 1];
    int sub = lane >> 4;   // edge slot 0..3
    int chunk = lane & 15; // 16B chunk in row
    float acc[8];
#pragma unroll
    for (int k = 0; k < 8; ++k) acc[k] = 0.f;
    int i = s + sub;
    for (; i + 4 < e; i += 8) {
        int c0 = col[i], c1 = col[i + 4];
        bf16x8 v0 = *(const bf16x8*)(m + (size_t)c0 * 128 + chunk * 8);
        bf16x8 v1 = *(const bf16x8*)(m + (size_t)c1 * 128 + chunk * 8);
#pragma unroll
        for (int k = 0; k < 8; ++k) {
            acc[k] += bf2f((ushort)v0[k]);
            acc[k] += bf2f((ushort)v1[k]);
        }
    }
    if (i < e) {
        int c0 = col[i];
        bf16x8 v0 = *(const bf16x8*)(m + (size_t)c0 * 128 + chunk * 8);
#pragma unroll
        for (int k = 0; k < 8; ++k) acc[k] += bf2f((ushort)v0[k]);
    }
#pragma unroll
    for (int k = 0; k < 8; ++k) {
        acc[k] += __shfl_xor(acc[k], 16);
        acc[k] += __shfl_xor(acc[k], 32);
    }
    if (sub == 0) {
        union { ushort u[8]; bf16x8 v; } o;
#pragma unroll
        for (int k = 0; k < 8; ++k) o.u[k] = f2bf(acc[k]);
        *(bf16x8*)(A + (size_t)node * 256 + chunk * 8) = o.v;
    }
}

// ---------------- fused GRU GEMM (K=256, LDS-staged A, fragment-order B) -----------

#define LDA 264
__global__ __launch_bounds__(256, 2) void k_gru_mfma(
    const ushort* __restrict__ A, const ushort* __restrict__ Bc2,
    const float* __restrict__ bias, float* __restrict__ h, ushort* Ah) {
    __shared__ ushort As[64 * LDA];
    int t = threadIdx.x;
    int rowb = blockIdx.x << 6;
    for (int c = t; c < 2048; c += 256) { // 64 rows x 32 chunks(16B)
        int r = c >> 5, off = (c & 31) * 8;
        *(bf16x8*)(As + r * LDA + off) =
            *(const bf16x8*)(A + (size_t)(rowb + r) * 256 + off);
    }
    __syncthreads();
    int w = t >> 6, lane = t & 63;
    int quad = lane >> 4, tn = lane & 15;
    f32x4 acc[4][4][2];
#pragma unroll
    for (int rt = 0; rt < 4; ++rt)
#pragma unroll
        for (int g = 0; g < 4; ++g)
#pragma unroll
            for (int c2 = 0; c2 < 2; ++c2) acc[rt][g][c2] = (f32x4){0.f, 0.f, 0.f, 0.f};
    for (int ks = 0; ks < 8; ++ks) {
        int k0 = ks * 32 + quad * 8;
        bf16x8 bfr[4][2];
#pragma unroll
        for (int g = 0; g < 4; ++g)
#pragma unroll
            for (int c2 = 0; c2 < 2; ++c2) {
                int ct = g * 8 + w * 2 + c2;
                bfr[g][c2] = *(const bf16x8*)(Bc2 + (size_t)((ct * 8 + ks) * 64 + lane) * 8);
            }
        bf16x8 af[4];
#pragma unroll
        for (int rt = 0; rt < 4; ++rt)
            af[rt] = *(const bf16x8*)(As + (rt * 16 + tn) * LDA + k0);
#pragma unroll
        for (int rt = 0; rt < 4; ++rt)
#pragma unroll
            for (int g = 0; g < 4; ++g)
#pragma unroll
                for (int c2 = 0; c2 < 2; ++c2)
                    acc[rt][g][c2] = __builtin_amdgcn_mfma_f32_16x16x32_bf16(
                        af[rt], bfr[g][c2], acc[rt][g][c2], 0, 0, 0);
    }
#pragma unroll
    for (int c2 = 0; c2 < 2; ++c2) {
        int cc = w * 32 + c2 * 16 + tn;
        float br = bias[cc], bz = bias[128 + cc], bin = bias[256 + cc], bhn = bias[384 + cc];
#pragma unroll
        for (int rt = 0; rt < 4; ++rt)
#pragma unroll
            for (int r = 0; r < 4; ++r) {
                int row = rowb + rt * 16 + quad * 4 + r;
                float ur = acc[rt][0][c2][r] + br;
                float uz = acc[rt][1][c2][r] + bz;
                float xin = acc[rt][2][c2][r] + bin;
                float xhn = acc[rt][3][c2][r] + bhn;
                float rr = 1.f / (1.f + __expf(-ur));
                float zz = 1.f / (1.f + __expf(-uz));
                float xt = xin + rr * xhn;
                float ex = __expf(2.f * fminf(fmaxf(xt, -15.f), 15.f));
                float nn = (ex - 1.f) / (ex + 1.f);
                float ho = h[row * 128 + cc];
                float hv = (1.f - zz) * nn + zz * ho;
                h[row * 128 + cc] = hv;
                Ah[row * 256 + cc] = f2bf(hv);
            }
    }
}

// ---------------- BN stats / finalize / pool / head ----------------

__global__ __launch_bounds__(256) void k_bnstats(const ushort* __restrict__ y,
                                                 float* __restrict__ stats, int N) {
    int half = threadIdx.x >> 7, f = threadIdx.x & 127;
    float s = 0.f, s2 = 0.f;
    for (int n = blockIdx.x * 2 + half; n < N; n += gridDim.x * 2) {
        float v = bf2f(y[n * HID + f]);
        s += v;
        s2 += v * v;
    }
    __shared__ float ls[2][HID], ls2[2][HID];
    ls[half][f] = s;
    ls2[half][f] = s2;
    __syncthreads();
    if (half == 0) {
        atomicAdd(&stats[f], ls[0][f] + ls[1][f]);
        atomicAdd(&stats[HID + f], ls2[0][f] + ls2[1][f]);
    }
}

__global__ void k_bnfinal(float* __restrict__ stats, const float* __restrict__ gamma,
                          const float* __restrict__ beta, float n) {
    int j = threadIdx.x;
    if (j < HID) {
        float mu = stats[j] / n;
        float var = stats[HID + j] / n - mu * mu;
        float sc = gamma[j] * rsqrtf(var + BN_EPS);
        stats[256 + j] = sc;
        stats[384 + j] = beta[j] - mu * sc;
    }
}

#define POOL_CHUNK 256
__global__ __launch_bounds__(128) void k_pool(const ushort* __restrict__ y,
                                              const float* __restrict__ stats,
                                              const int* __restrict__ batch,
                                              float* __restrict__ gsum,
                                              float* __restrict__ gcnt, int N) {
    int f = threadIdx.x;
    int start = blockIdx.x * POOL_CHUNK;
    if (start >= N) return;
    int end = min(start + POOL_CHUNK, N);
    float sc = stats[256 + f], sh = stats[384 + f];
    int cur = batch[start];
    float acc = 0.f, cnt = 0.f;
    for (int n = start; n < end; ++n) {
        int g = batch[n];
        if (g != cur) {
            atomicAdd(&gsum[cur * HID + f], acc);
            if (f == 0) atomicAdd(&gcnt[cur], cnt);
            acc = 0.f; cnt = 0.f; cur = g;
        }
        float v = bf2f(y[n * HID + f]) * sc + sh;
        acc += fmaxf(v, 0.f);
        cnt += 1.f;
    }
    atomicAdd(&gsum[cur * HID + f], acc);
    if (f == 0) atomicAdd(&gcnt[cur], cnt);
}

__global__ void k_head(const float* __restrict__ gsum, const float* __restrict__ gcnt,
                       const float* __restrict__ w2, const float* __restrict__ b2,
                       float* __restrict__ out) {
    int g = blockIdx.x * blockDim.x + threadIdx.x;
    if (g >= NGRAPHS) return;
    float inv = 1.0f / fmaxf(gcnt[g], 1.0f);
    float logits[NCLASSES];
    float mx = -1e30f;
    for (int c = 0; c < NCLASSES; ++c) {
        float acc = b2[c];
        for (int f = 0; f < HID; ++f) acc += gsum[g * HID + f] * inv * w2[c * HID + f];
        logits[c] = acc;
        mx = fmaxf(mx, acc);
    }
    float se = 0.f;
    for (int c = 0; c < NCLASSES; ++c) se += expf(logits[c] - mx);
    float lse = mx + logf(se);
    for (int c = 0; c < NCLASSES; ++c) out[g * NCLASSES + c] = logits[c] - lse;
}

// ---------------- launch ----------------

extern "C" void kernel_launch(void* const* d_in, const int* in_sizes, int n_in,
                              void* d_out, int out_size, void* d_ws, size_t ws_size,
                              hipStream_t stream) {
    const float* x     = (const float*)d_in[0];
    const int*   ei    = (const int*)d_in[1];
    const int*   batch = (const int*)d_in[2];
    const float* ggnnw = (const float*)d_in[3];
    const float* w_ih  = (const float*)d_in[4];
    const float* w_hh  = (const float*)d_in[5];
    const float* b_ih  = (const float*)d_in[6];
    const float* b_hh  = (const float*)d_in[7];
    const float* fc1_w = (const float*)d_in[8];
    // d_in[9] fc1_b: cancels exactly in training-mode BN -> unused
    const float* gamma = (const float*)d_in[10];
    const float* beta  = (const float*)d_in[11];
    const float* fc2_w = (const float*)d_in[12];
    const float* fc2_b = (const float*)d_in[13];
    float* out = (float*)d_out;

    const int N = in_sizes[0] / HID; // 100000
    const int E = in_sizes[1] / 2;   // 1600000
    const int nblk64 = (N + 63) / 64;
    const int P = nblk64 * 64;

    char* w = (char*)d_ws;
    auto alloc = [&](size_t bytes) -> char* {
        char* p = w;
        w += (bytes + 255) & ~(size_t)255;
        return p;
    };
    float*  h   = (float*)alloc(sizeof(float) * (size_t)P * HID);
    ushort* A   = (ushort*)alloc(sizeof(ushort) * (size_t)P * 256);
    ushort* m   = (ushort*)alloc(sizeof(ushort) * (size_t)P * HID);
    ushort* Bc2 = (ushort*)alloc(sizeof(ushort) * 512 * 256);
    ushort* Bg2 = (ushort*)alloc(sizeof(ushort) * NLAYERS * HID * HID);
    ushort* f1b = (ushort*)alloc(sizeof(ushort) * HID * HID);
    float*  bias = (float*)alloc(sizeof(float) * 512);
    int* rowstart = (int*)alloc(sizeof(int) * (N + 4));
    int* colb     = (int*)alloc(sizeof(int) * E);
    int* bsum     = (int*)alloc(sizeof(int) * 512);
    int* boff     = (int*)alloc(sizeof(int) * 512);
    size_t zelems = (size_t)N + N + 512 + NGRAPHS * HID + 256;
    char* zbase = alloc(zelems * 4);
    int*   deg    = (int*)zbase;
    int*   cursor = deg + N;
    float* stats  = (float*)(cursor + N);
    float* gsum   = stats + 512;
    float* gcnt   = gsum + NGRAPHS * HID;

    hipMemsetAsync(zbase, 0, zelems * 4, stream);

    k_init_x<<<(N * HID + 255) / 256, 256, 0, stream>>>(x, h, A, N);
    k_build_Bc<<<(512 * 256 + 255) / 256, 256, 0, stream>>>(w_ih, w_hh, Bc2);
    k_bias<<<1, 512, 0, stream>>>(b_ih, b_hh, bias);
    k_cvt_bg<<<(NLAYERS * 16384 + 255) / 256, 256, 0, stream>>>(ggnnw, Bg2);
    k_cvt_fc1<<<(16384 + 255) / 256, 256, 0, stream>>>(fc1_w, f1b);

    int nb1 = (N + 255) / 256;
    k_deg<<<(E + 255) / 256, 256, 0, stream>>>(ei, E, deg);
    k_scan1<<<nb1, 256, 0, stream>>>(deg, N, rowstart, bsum);
    k_scan2<<<1, 512, 0, stream>>>(bsum, nb1, boff);
    k_scan3<<<nb1, 256, 0, stream>>>(rowstart, boff, N, E);
    k_fill<<<(E + 255) / 256, 256, 0, stream>>>(ei, E, rowstart, cursor, colb);

    for (int l = 0; l < NLAYERS; ++l) {
        k_mm_mfma<<<nblk64, 256, 0, stream>>>(A + 128, 256, Bg2 + (size_t)l * HID * HID,
                                              m, nullptr);
        k_gather_bf<<<(N + 3) / 4, 256, 0, stream>>>(m, rowstart, colb, A, N);
        k_gru_mfma<<<nblk64, 256, 0, stream>>>(A, Bc2, bias, h, A + 128);
    }

    k_mm_mfma<<<nblk64, 256, 0, stream>>>(A + 128, 256, f1b, m, nullptr);
    k_bnstats<<<256, 256, 0, stream>>>(m, stats, N);
    k_bnfinal<<<1, 128, 0, stream>>>(stats, gamma, beta, (float)N);
    k_pool<<<(N + POOL_CHUNK - 1) / POOL_CHUNK, 128, 0, stream>>>(m, stats, batch, gsum, gcnt, N);
    k_head<<<1, 256, 0, stream>>>(gsum, gcnt, fc2_w, fc2_b, out);
}